// Round 1
// baseline (803.206 us; speedup 1.0000x reference)
//
#include <hip/hip_runtime.h>

// GCMCGraphConv: out[dst] = ci[dst] * sum_{e: dst_idx[e]==dst} weight[node_ids[src_idx[e]]] * cj[src_idx[e]]
// N_SRC = N_DST = 100000, N_EDGES = 3.2M, OUT_DIM = 64.

#define OUT_DIM 64

// One wave (64 lanes) per edge; lane = feature dim.
// src/dst/node_ids/cj loads are wave-uniform (same address -> broadcast),
// weight row gather + atomic scatter are fully coalesced 256B per wave.
__global__ void __launch_bounds__(256) gcmc_edge_scatter(
    const int* __restrict__ node_ids,
    const int* __restrict__ src_idx,
    const int* __restrict__ dst_idx,
    const float* __restrict__ cj,
    const float* __restrict__ weight,
    float* __restrict__ out,
    int n_edges) {
  const int lane = threadIdx.x & 63;
  const int waves_per_block = blockDim.x >> 6;
  const int wave = blockIdx.x * waves_per_block + (threadIdx.x >> 6);
  const int nwaves = gridDim.x * waves_per_block;

  for (int e = wave; e < n_edges; e += nwaves) {
    const int s = src_idx[e];
    const int d = dst_idx[e];
    const int row = node_ids[s];
    const float c = cj[s];
    const float v = weight[row * OUT_DIM + lane] * c;
    atomicAdd(&out[d * OUT_DIM + lane], v);
  }
}

__global__ void __launch_bounds__(256) gcmc_scale_ci(
    const float* __restrict__ ci,
    float* __restrict__ out,
    int n_elems) {
  const int i = blockIdx.x * blockDim.x + threadIdx.x;
  if (i < n_elems) {
    out[i] *= ci[i >> 6];  // i / OUT_DIM
  }
}

extern "C" void kernel_launch(void* const* d_in, const int* in_sizes, int n_in,
                              void* d_out, int out_size, void* d_ws, size_t ws_size,
                              hipStream_t stream) {
  const int* node_ids = (const int*)d_in[0];
  const int* src_idx  = (const int*)d_in[1];
  const int* dst_idx  = (const int*)d_in[2];
  const float* cj     = (const float*)d_in[3];
  const float* ci     = (const float*)d_in[4];
  const float* weight = (const float*)d_in[5];
  float* out = (float*)d_out;

  const int n_edges = in_sizes[1];
  // out_size = N_DST * OUT_DIM

  // 1) zero the (0xAA-poisoned) output accumulator
  hipMemsetAsync(d_out, 0, (size_t)out_size * sizeof(float), stream);

  // 2) edge scatter-add: one wave per edge, grid-stride
  {
    const int block = 256;                 // 4 waves/block
    const int grid = 4096;                 // grid-stride; 16 waves/CU of headroom
    gcmc_edge_scatter<<<grid, block, 0, stream>>>(node_ids, src_idx, dst_idx,
                                                  cj, weight, out, n_edges);
  }

  // 3) scale by ci
  {
    const int block = 256;
    const int grid = (out_size + block - 1) / block;
    gcmc_scale_ci<<<grid, block, 0, stream>>>(ci, out, out_size);
  }
}